// Round 2
// baseline (5707.947 us; speedup 1.0000x reference)
//
#include <hip/hip_runtime.h>
#include <hip/hip_bf16.h>
#include <hip/hip_fp16.h>

typedef __attribute__((ext_vector_type(8))) _Float16 f16x8;
typedef __attribute__((ext_vector_type(4))) float f32x4;

#define NSTEP 511

__device__ __forceinline__ unsigned short f2h(float f){ return __half_as_ushort(__float2half(f)); }
__device__ __forceinline__ float h2f(unsigned short u){ return __half2float(__ushort_as_half(u)); }
__device__ __forceinline__ float sigf(float z){ return 1.0f/(1.0f + __expf(-z)); }
__device__ __forceinline__ void gl_lds16(const void* g, void* l){
  __builtin_amdgcn_global_load_lds((const __attribute__((address_space(1))) unsigned int*)g,
                                   (__attribute__((address_space(3))) unsigned int*)l, 16, 0, 0);
}

// ---- gate tables: T[v][h] = sum_e emb[v,e]*w[e,h] + b[h], v in 0..2 ----
__global__ void k_tables(const float* __restrict__ emb, const float* __restrict__ w,
                         const float* __restrict__ bias, float* __restrict__ T){
  int h = blockIdx.x*256 + threadIdx.x;
  float a0=0.f, a1=0.f, a2=0.f;
  for(int e=0;e<512;e++){
    float we = w[e*1024 + h];
    a0 += emb[e]*we; a1 += emb[512+e]*we; a2 += emb[1024+e]*we;
  }
  float b = bias[h];
  T[h] = a0+b; T[1024+h] = a1+b; T[2048+h] = a2+b;
}

// ---- transpose 1024x1024 f32 -> f16 wT[n][k] = w[k][n] ----
__global__ void k_transpose(const float* __restrict__ w, unsigned short* __restrict__ wT){
  __shared__ float tile[64][65];
  int tr = blockIdx.x & 15, tc = blockIdx.x >> 4;
  int col = threadIdx.x & 63;
  int r0  = threadIdx.x >> 6;
  for(int rr=0; rr<16; rr++){
    int row = rr*4 + r0;
    tile[row][col] = w[(tr*64+row)*1024 + tc*64 + col];
  }
  __syncthreads();
  for(int rr=0; rr<16; rr++){
    int row = rr*4 + r0;
    wT[(tc*64+row)*1024 + tr*64 + col] = f2h(tile[col][row]);
  }
}

// ---- sequential recurrence: 256 WGs = 8 batch-groups x 32 col-slices ----
__global__ void __launch_bounds__(512,1) k_recur(
    const int* __restrict__ x,
    const unsigned short* __restrict__ wTi,   // w_ih^T f16 [n][k]
    const unsigned short* __restrict__ wTf,
    const unsigned short* __restrict__ wTo,
    const float* __restrict__ Ti, const float* __restrict__ Tf,
    const float* __restrict__ To, const float* __restrict__ Tc,
    unsigned short* __restrict__ cbf,         // [2][256][1024] f16 (hi, lo planes)
    float* __restrict__ hbuf,
    unsigned int* __restrict__ bars)
{
  __shared__ __align__(16) unsigned char smem[163840];
  unsigned char* Wl  = smem;                 // 131072: [2 gates][32 n][2048B k] swizzled
  unsigned char* buf = smem + 131072;        // 2 x 16384 stage buffers (each: 2 planes x 8KB)

  const int tid  = threadIdx.x;
  const int wid  = tid >> 6;
  const int lane = tid & 63;
  const int mg   = blockIdx.x & 7;
  const int ng   = blockIdx.x >> 3;
  const int mbase = mg*32;
  const int nbase = ng*32;

  // weights -> LDS (swizzle: byte ^= (n&7)<<4 within 2048B row)
  #pragma unroll
  for(int i=0;i<16;i++){
    int c  = tid + i*512;
    int g  = c >> 12;
    int cc = c & 4095;
    int nl = cc >> 7;
    int kc = cc & 127;
    const unsigned short* src = (g ? wTf : wTi) + (nbase+nl)*1024 + kc*8;
    uint4 v = *reinterpret_cast<const uint4*>(src);
    unsigned dst = (unsigned)(g*65536) + (((unsigned)(nl*2048 + kc*16)) ^ (((unsigned)(nl&7))<<4));
    *reinterpret_cast<uint4*>(Wl + dst) = v;
  }

  const int b_l = tid >> 4;            // owned batch row 0..31
  const int h_l = (tid & 15)*2;        // owned col pair in slice
  const int bg  = mbase + b_l;

  // gate tables -> registers (24 floats: [4 gates][3 v][2 cols])
  float tT[4][3][2];
  { const float* Tp[4] = {Ti, Tf, Tc, To};
    #pragma unroll
    for(int g=0; g<4; g++)
      #pragma unroll
      for(int v=0; v<3; v++)
        #pragma unroll
        for(int j=0; j<2; j++) tT[g][v][j] = Tp[g][v*1024 + nbase + h_l + j];
  }
  float cm0 = 0.f, cm1 = 0.f;          // master c in f32

  const int g_w  = wid & 1;
  const int mh_w = (wid>>1)&1;
  const int nh_w = (wid>>2)&1;
  const int arow = mh_w*16 + (lane&15);
  const int acol = (lane>>4)*8;
  const int nloc = nh_w*16 + (lane&15);
  const unsigned wswz = ((unsigned)(nloc&7))<<4;
  const unsigned aswz = ((unsigned)(arow&7))<<4;
  const unsigned char* wbase = Wl + g_w*65536 + nloc*2048;
  const int orow = ((wid&1)<<4) + (lane&15);
  const unsigned oswz = ((unsigned)(orow&7))<<4;
  const int ocol = nbase + ((wid>>1)&1)*16 + (lane&15);

  // staging geometry: chunk cc = wid*64+lane of 512 per plane; inverse-swizzled global src
  const int cc_s  = wid*64 + lane;
  const int row_s = cc_s >> 4;
  const int kc_s  = (cc_s & 15) ^ (row_s & 7);
  const unsigned short* aSrc0 = cbf          + (mbase+row_s)*1024 + kc_s*8;  // hi plane
  const unsigned short* aSrc1 = cbf + 262144 + (mbase+row_s)*1024 + kc_s*8;  // lo plane

  unsigned int* bar = bars + mg*64;

  __syncthreads();   // weights ready

  for(int t=0; t<NSTEP; t++){
    const bool last = (t == NSTEP-1);
    const int v = x[bg*512 + t];
    f32x4 aH={0.f,0.f,0.f,0.f}, aL={0.f,0.f,0.f,0.f};
    f32x4 oH={0.f,0.f,0.f,0.f}, oL={0.f,0.f,0.f,0.f};

    // prologue: issue phase-0 stage into buf0
    gl_lds16(aSrc0, buf + wid*1024);
    gl_lds16(aSrc1, buf + 8192 + wid*1024);

    #pragma unroll 1
    for(int p=0;p<8;p++){
      asm volatile("s_waitcnt vmcnt(0)" ::: "memory");
      __syncthreads();                 // phase p staged; everyone done reading buf[p-1]
      if(p<7){
        int bsel = (p+1)&1;
        gl_lds16(aSrc0 + (p+1)*128, buf + bsel*16384        + wid*1024);
        gl_lds16(aSrc1 + (p+1)*128, buf + bsel*16384 + 8192 + wid*1024);
      }
      const unsigned char* bufc = buf + (p&1)*16384;
      #pragma unroll
      for(int kk=0;kk<4;kk++){
        int kb = (kk*32 + acol)*2;
        f16x8 bb = *reinterpret_cast<const f16x8*>(wbase + (((unsigned)((p*128 + kk*32 + acol)*2)) ^ wswz));
        f16x8 ah = *reinterpret_cast<const f16x8*>(bufc        + (((unsigned)(arow*256 + kb)) ^ aswz));
        f16x8 al = *reinterpret_cast<const f16x8*>(bufc + 8192 + (((unsigned)(arow*256 + kb)) ^ aswz));
        aH = __builtin_amdgcn_mfma_f32_16x16x32_f16(ah, bb, aH, 0,0,0);
        aL = __builtin_amdgcn_mfma_f32_16x16x32_f16(al, bb, aL, 0,0,0);
      }
      if(last && wid < 4){
        #pragma unroll
        for(int kk=0;kk<4;kk++){
          int kb = (kk*32 + acol)*2;
          f16x8 bo = *reinterpret_cast<const f16x8*>(wTo + ocol*1024 + p*128 + kk*32 + acol);
          f16x8 ah = *reinterpret_cast<const f16x8*>(bufc        + (((unsigned)(orow*256 + kb)) ^ oswz));
          f16x8 al = *reinterpret_cast<const f16x8*>(bufc + 8192 + (((unsigned)(orow*256 + kb)) ^ oswz));
          oH = __builtin_amdgcn_mfma_f32_16x16x32_f16(ah, bo, oH, 0,0,0);
          oL = __builtin_amdgcn_mfma_f32_16x16x32_f16(al, bo, oL, 0,0,0);
        }
      }
    }
    // exchange accumulators through buf0 (phase 7 read buf1 -> disjoint)
    float* xch = reinterpret_cast<float*>(buf);
    { f32x4 at = aH + aL;
      *reinterpret_cast<f32x4*>(xch + wid*256 + lane*4) = at;
      if(last && wid < 4){ f32x4 ot = oH + oL;
        *reinterpret_cast<f32x4*>(xch + (8+wid)*256 + lane*4) = ot; } }
    __syncthreads();

    // elementwise update: each thread owns 2 c elements
    {
      int r16 = b_l & 15;
      int mh  = b_l >> 4;
      int reg = r16 & 3;
      int lq  = r16 >> 2;
      float cn[2], hh[2];
      #pragma unroll
      for(int j=0;j<2;j++){
        int col = h_l + j;
        int nh  = col >> 4;
        int l   = (lq<<4) | (col & 15);
        float mi = xch[((mh<<1) + (nh<<2)    )*256 + l*4 + reg];
        float mf = xch[((mh<<1) + (nh<<2) + 1)*256 + l*4 + reg];
        float ti = (v==0) ? tT[0][0][j] : (v==1) ? tT[0][1][j] : tT[0][2][j];
        float tf = (v==0) ? tT[1][0][j] : (v==1) ? tT[1][1][j] : tT[1][2][j];
        float tc = (v==0) ? tT[2][0][j] : (v==1) ? tT[2][1][j] : tT[2][2][j];
        float iv = sigf(ti + mi);
        float fv = sigf(tf + mf);
        float cv = sigf(tc);
        float cm = j ? cm1 : cm0;
        float c2 = cv*iv + cm*fv;
        cn[j] = c2;
        if(last){
          float to = (v==0) ? tT[3][0][j] : (v==1) ? tT[3][1][j] : tT[3][2][j];
          float mo = xch[(8 + mh + (nh<<1))*256 + l*4 + reg];
          float ov = sigf(to + mo);
          float pad = (float)((v+1)>>1);
          hh[j] = tanhf(c2)*ov*pad;
        }
      }
      if(!last){
        cm0 = cn[0]; cm1 = cn[1];
        unsigned short h0 = f2h(cn[0]), h1 = f2h(cn[1]);
        float r0 = cn[0] - h2f(h0);
        float r1 = cn[1] - h2f(h1);
        unsigned pkh = (unsigned)h0 | (((unsigned)h1)<<16);
        unsigned pkl = (unsigned)f2h(r0) | (((unsigned)f2h(r1))<<16);
        *reinterpret_cast<unsigned*>(cbf + bg*1024 + nbase + h_l) = pkh;
        *reinterpret_cast<unsigned*>(cbf + 262144 + bg*1024 + nbase + h_l) = pkl;
      } else {
        *reinterpret_cast<float2*>(hbuf + bg*1024 + nbase + h_l) = make_float2(hh[0], hh[1]);
      }
    }

    if(!last){
      __syncthreads();                 // all publishes done (WG scope)
      if(tid == 0){
        __hip_atomic_fetch_add(bar, 1u, __ATOMIC_RELEASE, __HIP_MEMORY_SCOPE_AGENT);
        unsigned tgt = 32u*(unsigned)(t+1);
        unsigned cur;
        do {
          cur = __hip_atomic_load(bar, __ATOMIC_RELAXED, __HIP_MEMORY_SCOPE_AGENT);
        } while(cur < tgt);
        (void)__hip_atomic_load(bar, __ATOMIC_ACQUIRE, __HIP_MEMORY_SCOPE_AGENT);
      }
      __syncthreads();
    }
  }
}

// ---- projection + log_softmax over axis 0 (batch) ----
__global__ void k_proj(const float* __restrict__ hbuf, const float* __restrict__ w_ph,
                       const float* __restrict__ b_p, float* __restrict__ out){
  const int c = blockIdx.x;    // 0..9
  const int b = threadIdx.x;   // 0..255
  float acc = b_p[c];
  const float4* hb = reinterpret_cast<const float4*>(hbuf + b*1024);
  for(int i=0;i<256;i++){
    float4 hv = hb[i];
    int h = i*4;
    acc += hv.x*w_ph[h*10+c] + hv.y*w_ph[(h+1)*10+c] + hv.z*w_ph[(h+2)*10+c] + hv.w*w_ph[(h+3)*10+c];
  }
  __shared__ float red[256];
  red[b] = acc; __syncthreads();
  for(int s=128;s>0;s>>=1){ if(b<s) red[b]=fmaxf(red[b],red[b+s]); __syncthreads(); }
  float m = red[0]; __syncthreads();
  red[b] = expf(acc-m); __syncthreads();
  for(int s=128;s>0;s>>=1){ if(b<s) red[b]+=red[b+s]; __syncthreads(); }
  out[b*10+c] = acc - m - logf(red[0]);
}

extern "C" void kernel_launch(void* const* d_in, const int* in_sizes, int n_in,
                              void* d_out, int out_size, void* d_ws, size_t ws_size,
                              hipStream_t stream){
  const int*   x    = (const int*)  d_in[0];
  const float* emb  = (const float*)d_in[1];
  const float* w_cx = (const float*)d_in[2];
  const float* b_c  = (const float*)d_in[3];
  const float* w_ix = (const float*)d_in[4];
  const float* w_ih = (const float*)d_in[5];
  const float* b_i  = (const float*)d_in[6];
  const float* w_fx = (const float*)d_in[7];
  const float* w_fh = (const float*)d_in[8];
  const float* b_f  = (const float*)d_in[9];
  const float* w_ox = (const float*)d_in[10];
  const float* w_oh = (const float*)d_in[11];
  const float* b_o  = (const float*)d_in[12];
  const float* w_ph = (const float*)d_in[13];
  const float* b_p  = (const float*)d_in[14];
  float* out = (float*)d_out;

  char* ws = (char*)d_ws;
  float* Ti = (float*)(ws);
  float* Tf = (float*)(ws + 12288);
  float* To = (float*)(ws + 24576);
  float* Tc = (float*)(ws + 36864);
  unsigned short* wTi = (unsigned short*)(ws + 49152);
  unsigned short* wTf = (unsigned short*)(ws + 2146304);
  unsigned short* wTo = (unsigned short*)(ws + 4243456);
  unsigned short* cbf = (unsigned short*)(ws + 6340608);  // 2 planes x 512KB
  unsigned int*  bars = (unsigned int*) (ws + 7389184);
  float* hbuf = (float*)(ws + 7391232);

  hipMemsetAsync(cbf, 0, 1048576 + 2048, stream);   // c planes + barrier counters
  k_tables<<<4,256,0,stream>>>(emb, w_ix, b_i, Ti);
  k_tables<<<4,256,0,stream>>>(emb, w_fx, b_f, Tf);
  k_tables<<<4,256,0,stream>>>(emb, w_ox, b_o, To);
  k_tables<<<4,256,0,stream>>>(emb, w_cx, b_c, Tc);
  k_transpose<<<256,256,0,stream>>>(w_ih, wTi);
  k_transpose<<<256,256,0,stream>>>(w_fh, wTf);
  k_transpose<<<256,256,0,stream>>>(w_oh, wTo);

  void* args[] = { (void*)&x, (void*)&wTi, (void*)&wTf, (void*)&wTo,
                   (void*)&Ti, (void*)&Tf, (void*)&To, (void*)&Tc,
                   (void*)&cbf, (void*)&hbuf, (void*)&bars };
  hipLaunchCooperativeKernel((void*)k_recur, dim3(256), dim3(512), args, 0, stream);
  k_proj<<<10,256,0,stream>>>(hbuf, w_ph, b_p, out);
}

// Round 3
// 4880.225 us; speedup vs baseline: 1.1696x; 1.1696x over previous
//
#include <hip/hip_runtime.h>
#include <hip/hip_bf16.h>
#include <hip/hip_fp16.h>

typedef __attribute__((ext_vector_type(8))) _Float16 f16x8;
typedef __attribute__((ext_vector_type(4))) float f32x4;

#define NSTEP 511

__device__ __forceinline__ unsigned short f2h(float f){ return __half_as_ushort(__float2half(f)); }
__device__ __forceinline__ float sigf(float z){ return 1.0f/(1.0f + __expf(-z)); }
__device__ __forceinline__ void gl_lds16(const void* g, void* l){
  __builtin_amdgcn_global_load_lds((const __attribute__((address_space(1))) unsigned int*)g,
                                   (__attribute__((address_space(3))) unsigned int*)l, 16, 0, 0);
}

// ---- gate tables: T[v][h] = sum_e emb[v,e]*w[e,h] + b[h], v in 0..2 ----
__global__ void k_tables(const float* __restrict__ emb, const float* __restrict__ w,
                         const float* __restrict__ bias, float* __restrict__ T){
  int h = blockIdx.x*256 + threadIdx.x;
  float a0=0.f, a1=0.f, a2=0.f;
  for(int e=0;e<512;e++){
    float we = w[e*1024 + h];
    a0 += emb[e]*we; a1 += emb[512+e]*we; a2 += emb[1024+e]*we;
  }
  float b = bias[h];
  T[h] = a0+b; T[1024+h] = a1+b; T[2048+h] = a2+b;
}

// ---- transpose 1024x1024 f32 -> f16 wT[n][k] = w[k][n] ----
__global__ void k_transpose(const float* __restrict__ w, unsigned short* __restrict__ wT){
  __shared__ float tile[64][65];
  int tr = blockIdx.x & 15, tc = blockIdx.x >> 4;
  int col = threadIdx.x & 63;
  int r0  = threadIdx.x >> 6;
  for(int rr=0; rr<16; rr++){
    int row = rr*4 + r0;
    tile[row][col] = w[(tr*64+row)*1024 + tc*64 + col];
  }
  __syncthreads();
  for(int rr=0; rr<16; rr++){
    int row = rr*4 + r0;
    wT[(tc*64+row)*1024 + tr*64 + col] = f2h(tile[col][row]);
  }
}

// ---- sequential recurrence: 256 WGs = 8 batch-groups x 32 col-slices ----
// Waves: wid = q*2 + mh ; q = k-quarter (256 k), mh = 16-row half.
// B (w_ih,w_fh columns) lives in VGPRs; A (c) staged 64KB to LDS once/step.
__global__ void __launch_bounds__(512,2) k_recur(
    const int* __restrict__ x,
    const unsigned short* __restrict__ wTi,   // w_ih^T f16 [n][k]
    const unsigned short* __restrict__ wTf,
    const unsigned short* __restrict__ wTo,
    const float* __restrict__ Ti, const float* __restrict__ Tf,
    const float* __restrict__ To, const float* __restrict__ Tc,
    unsigned short* __restrict__ cbf,         // [256][1024] f16
    float* __restrict__ hbuf,
    unsigned int* __restrict__ bars)
{
  __shared__ __align__(16) unsigned char smem[114688];
  unsigned char* As  = smem;                       // 65536: [4 q][32 row][512B] swizzled
  float* xch = reinterpret_cast<float*>(smem + 65536);  // 32768: 32 slots x 1KB
  float* xo  = reinterpret_cast<float*>(smem + 98304);  // 16384: 16 slots (o, last step)

  const int tid  = threadIdx.x;
  const int wid  = tid >> 6;
  const int lane = tid & 63;
  const int mg   = blockIdx.x & 7;
  const int ng   = blockIdx.x >> 3;
  const int mbase = mg*32;
  const int nbase = ng*32;

  const int mh_w = wid & 1;
  const int q_w  = wid >> 1;

  // ---- load B (both gates, both 16-col halves, this wave's k-quarter) into regs ----
  const int bcol0 = nbase + (lane&15);
  const int bcol1 = nbase + 16 + (lane&15);
  const int bk    = q_w*256 + (lane>>4)*8;
  f16x8 Bi0[8], Bi1[8], Bf0[8], Bf1[8];
  #pragma unroll
  for(int kk=0;kk<8;kk++){
    Bi0[kk] = *reinterpret_cast<const f16x8*>(wTi + bcol0*1024 + bk + kk*32);
    Bi1[kk] = *reinterpret_cast<const f16x8*>(wTi + bcol1*1024 + bk + kk*32);
    Bf0[kk] = *reinterpret_cast<const f16x8*>(wTf + bcol0*1024 + bk + kk*32);
    Bf1[kk] = *reinterpret_cast<const f16x8*>(wTf + bcol1*1024 + bk + kk*32);
  }

  const int b_l = tid >> 4;            // owned batch row 0..31
  const int h_l = (tid & 15)*2;        // owned col pair in slice
  const int bg  = mbase + b_l;

  // gate tables i,f,c -> registers
  float tT[3][3][2];
  { const float* Tp[3] = {Ti, Tf, Tc};
    #pragma unroll
    for(int g=0; g<3; g++)
      #pragma unroll
      for(int v=0; v<3; v++)
        #pragma unroll
        for(int j=0; j<2; j++) tT[g][v][j] = Tp[g][v*1024 + nbase + h_l + j];
  }
  float cm0 = 0.f, cm1 = 0.f;          // master c in f32

  const int arow  = mh_w*16 + (lane&15);
  const int acol2 = (lane>>4)*16;      // byte offset of k-chunk
  const unsigned aswz = ((unsigned)(arow&7))<<4;
  const unsigned char* Aq = As + q_w*16384;

  unsigned int* arr = bars + mg*64;    // 64 dwords per group; slot ng

  __syncthreads();
  int vc = x[bg*512];                  // v for t=0

  for(int t=0; t<NSTEP; t++){
    const bool last = (t == NSTEP-1);

    // ---- stage A slab (64KB): 8 gl_lds per thread, quarter-major, swizzled src ----
    #pragma unroll
    for(int i=0;i<8;i++){
      int c   = i*512 + tid;
      int q   = c >> 10;
      int row = (c >> 5) & 31;
      int k16 = c & 31;
      const unsigned short* src = cbf + (mbase+row)*1024 + q*256 + ((k16 ^ (row&7))<<3);
      gl_lds16(src, As + i*8192 + wid*1024);
    }
    int vn = last ? 0 : x[bg*512 + t + 1];
    asm volatile("s_waitcnt vmcnt(0)" ::: "memory");
    __syncthreads();

    // ---- compute: 8 A-fragments, 32 MFMA (i,f x 2 col-halves x 8 k-slices) ----
    f16x8 ah[8];
    #pragma unroll
    for(int kk=0;kk<8;kk++){
      unsigned off = ((unsigned)(arow*512 + kk*64 + acol2)) ^ aswz;
      ah[kk] = *reinterpret_cast<const f16x8*>(Aq + off);
    }
    f32x4 a00={0.f,0.f,0.f,0.f}, a01={0.f,0.f,0.f,0.f};
    f32x4 a10={0.f,0.f,0.f,0.f}, a11={0.f,0.f,0.f,0.f};
    #pragma unroll
    for(int kk=0;kk<8;kk++){
      a00 = __builtin_amdgcn_mfma_f32_16x16x32_f16(ah[kk], Bi0[kk], a00, 0,0,0);
      a01 = __builtin_amdgcn_mfma_f32_16x16x32_f16(ah[kk], Bi1[kk], a01, 0,0,0);
      a10 = __builtin_amdgcn_mfma_f32_16x16x32_f16(ah[kk], Bf0[kk], a10, 0,0,0);
      a11 = __builtin_amdgcn_mfma_f32_16x16x32_f16(ah[kk], Bf1[kk], a11, 0,0,0);
    }
    *reinterpret_cast<f32x4*>(xch + (wid*4 + 0)*256 + lane*4) = a00;
    *reinterpret_cast<f32x4*>(xch + (wid*4 + 1)*256 + lane*4) = a01;
    *reinterpret_cast<f32x4*>(xch + (wid*4 + 2)*256 + lane*4) = a10;
    *reinterpret_cast<f32x4*>(xch + (wid*4 + 3)*256 + lane*4) = a11;
    if(last){
      f32x4 o0={0.f,0.f,0.f,0.f}, o1={0.f,0.f,0.f,0.f};
      #pragma unroll
      for(int kk=0;kk<8;kk++){
        f16x8 bo0 = *reinterpret_cast<const f16x8*>(wTo + bcol0*1024 + bk + kk*32);
        f16x8 bo1 = *reinterpret_cast<const f16x8*>(wTo + bcol1*1024 + bk + kk*32);
        o0 = __builtin_amdgcn_mfma_f32_16x16x32_f16(ah[kk], bo0, o0, 0,0,0);
        o1 = __builtin_amdgcn_mfma_f32_16x16x32_f16(ah[kk], bo1, o1, 0,0,0);
      }
      *reinterpret_cast<f32x4*>(xo + (wid*2 + 0)*256 + lane*4) = o0;
      *reinterpret_cast<f32x4*>(xo + (wid*2 + 1)*256 + lane*4) = o1;
    }
    __syncthreads();

    // ---- elementwise update: each thread owns 2 c elements ----
    {
      const int v = vc;
      int r16 = b_l & 15;
      int mh  = b_l >> 4;
      int reg = r16 & 3;
      int lq  = r16 >> 2;
      float cn[2], hh[2];
      #pragma unroll
      for(int j=0;j<2;j++){
        int col = h_l + j;
        int nh  = col >> 4;
        int l   = (lq<<4) | (col & 15);
        float mi = 0.f, mf = 0.f;
        #pragma unroll
        for(int q=0;q<4;q++){
          const float* base = xch + ((q*2+mh)*4 + nh)*256 + l*4 + reg;
          mi += base[0];
          mf += base[512];
        }
        float ti = (v==0)?tT[0][0][j]:(v==1)?tT[0][1][j]:tT[0][2][j];
        float tf = (v==0)?tT[1][0][j]:(v==1)?tT[1][1][j]:tT[1][2][j];
        float tc = (v==0)?tT[2][0][j]:(v==1)?tT[2][1][j]:tT[2][2][j];
        float iv = sigf(ti + mi);
        float fv = sigf(tf + mf);
        float cv = sigf(tc);
        float cm = j ? cm1 : cm0;
        float c2 = cv*iv + cm*fv;
        cn[j] = c2;
        if(last){
          float mo = 0.f;
          #pragma unroll
          for(int q=0;q<4;q++) mo += xo[((q*2+mh)*2 + nh)*256 + l*4 + reg];
          float to = To[v*1024 + nbase + col];
          float ov = sigf(to + mo);
          float pad = (float)((v+1)>>1);
          hh[j] = tanhf(c2)*ov*pad;
        }
      }
      if(!last){
        cm0 = cn[0]; cm1 = cn[1];
        unsigned pk = (unsigned)f2h(cn[0]) | (((unsigned)f2h(cn[1]))<<16);
        *reinterpret_cast<unsigned*>(cbf + bg*1024 + nbase + h_l) = pk;
      } else {
        *reinterpret_cast<float2*>(hbuf + bg*1024 + nbase + h_l) = make_float2(hh[0], hh[1]);
      }
    }

    if(!last){
      __syncthreads();   // drains each wave's publish stores (vmcnt 0) before barrier
      if(tid == 0)
        __hip_atomic_store(&arr[ng], (unsigned)(t+1), __ATOMIC_RELEASE, __HIP_MEMORY_SCOPE_AGENT);
      if(wid == 0){
        const unsigned tgt = (unsigned)(t+1);
        unsigned int* slot = &arr[lane & 31];
        while(__hip_atomic_load(slot, __ATOMIC_RELAXED, __HIP_MEMORY_SCOPE_AGENT) < tgt)
          __builtin_amdgcn_s_sleep(1);
        (void)__hip_atomic_load(&arr[0], __ATOMIC_ACQUIRE, __HIP_MEMORY_SCOPE_AGENT);
      }
      __syncthreads();
    }
    vc = vn;
  }
}

// ---- projection + log_softmax over axis 0 (batch) ----
__global__ void k_proj(const float* __restrict__ hbuf, const float* __restrict__ w_ph,
                       const float* __restrict__ b_p, float* __restrict__ out){
  const int c = blockIdx.x;    // 0..9
  const int b = threadIdx.x;   // 0..255
  float acc = b_p[c];
  const float4* hb = reinterpret_cast<const float4*>(hbuf + b*1024);
  for(int i=0;i<256;i++){
    float4 hv = hb[i];
    int h = i*4;
    acc += hv.x*w_ph[h*10+c] + hv.y*w_ph[(h+1)*10+c] + hv.z*w_ph[(h+2)*10+c] + hv.w*w_ph[(h+3)*10+c];
  }
  __shared__ float red[256];
  red[b] = acc; __syncthreads();
  for(int s=128;s>0;s>>=1){ if(b<s) red[b]=fmaxf(red[b],red[b+s]); __syncthreads(); }
  float m = red[0]; __syncthreads();
  red[b] = expf(acc-m); __syncthreads();
  for(int s=128;s>0;s>>=1){ if(b<s) red[b]+=red[b+s]; __syncthreads(); }
  out[b*10+c] = acc - m - logf(red[0]);
}

extern "C" void kernel_launch(void* const* d_in, const int* in_sizes, int n_in,
                              void* d_out, int out_size, void* d_ws, size_t ws_size,
                              hipStream_t stream){
  const int*   x    = (const int*)  d_in[0];
  const float* emb  = (const float*)d_in[1];
  const float* w_cx = (const float*)d_in[2];
  const float* b_c  = (const float*)d_in[3];
  const float* w_ix = (const float*)d_in[4];
  const float* w_ih = (const float*)d_in[5];
  const float* b_i  = (const float*)d_in[6];
  const float* w_fx = (const float*)d_in[7];
  const float* w_fh = (const float*)d_in[8];
  const float* b_f  = (const float*)d_in[9];
  const float* w_ox = (const float*)d_in[10];
  const float* w_oh = (const float*)d_in[11];
  const float* b_o  = (const float*)d_in[12];
  const float* w_ph = (const float*)d_in[13];
  const float* b_p  = (const float*)d_in[14];
  float* out = (float*)d_out;

  char* ws = (char*)d_ws;
  float* Ti = (float*)(ws);
  float* Tf = (float*)(ws + 12288);
  float* To = (float*)(ws + 24576);
  float* Tc = (float*)(ws + 36864);
  unsigned short* wTi = (unsigned short*)(ws + 49152);
  unsigned short* wTf = (unsigned short*)(ws + 2146304);
  unsigned short* wTo = (unsigned short*)(ws + 4243456);
  unsigned short* cbf = (unsigned short*)(ws + 6340608);  // 512 KB, f16 [256][1024]
  unsigned int*  bars = (unsigned int*) (ws + 6864896);   // 8 groups x 64 dwords
  float* hbuf = (float*)(ws + 6866944);

  hipMemsetAsync(cbf, 0, 524288 + 2048, stream);   // c plane + barrier slots
  k_tables<<<4,256,0,stream>>>(emb, w_ix, b_i, Ti);
  k_tables<<<4,256,0,stream>>>(emb, w_fx, b_f, Tf);
  k_tables<<<4,256,0,stream>>>(emb, w_ox, b_o, To);
  k_tables<<<4,256,0,stream>>>(emb, w_cx, b_c, Tc);
  k_transpose<<<256,256,0,stream>>>(w_ih, wTi);
  k_transpose<<<256,256,0,stream>>>(w_fh, wTf);
  k_transpose<<<256,256,0,stream>>>(w_oh, wTo);

  void* args[] = { (void*)&x, (void*)&wTi, (void*)&wTf, (void*)&wTo,
                   (void*)&Ti, (void*)&Tf, (void*)&To, (void*)&Tc,
                   (void*)&cbf, (void*)&hbuf, (void*)&bars };
  hipLaunchCooperativeKernel((void*)k_recur, dim3(256), dim3(512), args, 0, stream);
  k_proj<<<10,256,0,stream>>>(hbuf, w_ph, b_p, out);
}

// Round 5
// 2498.895 us; speedup vs baseline: 2.2842x; 1.9530x over previous
//
#include <hip/hip_runtime.h>
#include <hip/hip_bf16.h>
#include <hip/hip_fp16.h>

typedef __attribute__((ext_vector_type(8))) _Float16 f16x8;
typedef __attribute__((ext_vector_type(4))) float f32x4;

#define NSTEP 511

__device__ __forceinline__ unsigned short f2h(float f){ return __half_as_ushort(__float2half(f)); }
__device__ __forceinline__ float sigf(float z){ return 1.0f/(1.0f + __expf(-z)); }

// Agent-coherent primitives: sc0 sc1 bypasses L1/L2, served by the memory-side
// L3 (coherent across XCDs). No cache-maintenance fences needed anywhere.
__device__ __forceinline__ void st32_coh(unsigned* p, unsigned v){
  asm volatile("global_store_dword %0, %1, off sc0 sc1\n\ts_waitcnt vmcnt(0)"
               :: "v"(p), "v"(v) : "memory");
}
__device__ __forceinline__ unsigned ld32_coh(const unsigned* p){
  unsigned v;
  asm volatile("global_load_dword %0, %1, off sc0 sc1\n\ts_waitcnt vmcnt(0)"
               : "=v"(v) : "v"(p) : "memory");
  return v;
}
// 8x16B coherent loads + in-block waitcnt (consumers are safe after the block).
__device__ __forceinline__ void ldA8_coh(const void* p, f16x8 a[8]){
  asm volatile(
    "global_load_dwordx4 %0, %8, off sc0 sc1\n\t"
    "global_load_dwordx4 %1, %8, off offset:64 sc0 sc1\n\t"
    "global_load_dwordx4 %2, %8, off offset:128 sc0 sc1\n\t"
    "global_load_dwordx4 %3, %8, off offset:192 sc0 sc1\n\t"
    "global_load_dwordx4 %4, %8, off offset:256 sc0 sc1\n\t"
    "global_load_dwordx4 %5, %8, off offset:320 sc0 sc1\n\t"
    "global_load_dwordx4 %6, %8, off offset:384 sc0 sc1\n\t"
    "global_load_dwordx4 %7, %8, off offset:448 sc0 sc1\n\t"
    "s_waitcnt vmcnt(0)"
    : "=v"(a[0]),"=v"(a[1]),"=v"(a[2]),"=v"(a[3]),
      "=v"(a[4]),"=v"(a[5]),"=v"(a[6]),"=v"(a[7])
    : "v"(p) : "memory");
}

// ---- gate tables: T[v][h] = sum_e emb[v,e]*w[e,h] + b[h], v in 0..2 ----
__global__ void k_tables(const float* __restrict__ emb, const float* __restrict__ w,
                         const float* __restrict__ bias, float* __restrict__ T){
  int h = blockIdx.x*256 + threadIdx.x;
  float a0=0.f, a1=0.f, a2=0.f;
  for(int e=0;e<512;e++){
    float we = w[e*1024 + h];
    a0 += emb[e]*we; a1 += emb[512+e]*we; a2 += emb[1024+e]*we;
  }
  float b = bias[h];
  T[h] = a0+b; T[1024+h] = a1+b; T[2048+h] = a2+b;
}

// ---- transpose 1024x1024 f32 -> f16 wT[n][k] = w[k][n] ----
__global__ void k_transpose(const float* __restrict__ w, unsigned short* __restrict__ wT){
  __shared__ float tile[64][65];
  int tr = blockIdx.x & 15, tc = blockIdx.x >> 4;
  int col = threadIdx.x & 63;
  int r0  = threadIdx.x >> 6;
  for(int rr=0; rr<16; rr++){
    int row = rr*4 + r0;
    tile[row][col] = w[(tr*64+row)*1024 + tc*64 + col];
  }
  __syncthreads();
  for(int rr=0; rr<16; rr++){
    int row = rr*4 + r0;
    wT[(tc*64+row)*1024 + tr*64 + col] = f2h(tile[col][row]);
  }
}

// ---- sequential recurrence: 256 WGs = 8 batch-groups x 32 col-slices ----
// All cross-WG data via sc0/sc1 (L3-coherent). Per-wave producer polling:
// wave of k-quarter q waits only on flags of the 8 WGs producing its columns.
// c double-buffered: step t reads plane (t&1), writes plane ((t+1)&1).
__global__ void __launch_bounds__(512,1) k_recur(
    const int* __restrict__ x,
    const unsigned short* __restrict__ wTi,   // w_ih^T f16 [n][k]
    const unsigned short* __restrict__ wTf,
    const unsigned short* __restrict__ wTo,
    const float* __restrict__ Ti, const float* __restrict__ Tf,
    const float* __restrict__ To, const float* __restrict__ Tc,
    unsigned short* __restrict__ cbf,         // [2][256][1024] f16 planes
    float* __restrict__ hbuf,
    unsigned int* __restrict__ bars)          // [8 grp][64] flags
{
  __shared__ __align__(16) float xch[8192];   // 32KB accumulator exchange
  __shared__ __align__(16) float xo[4096];    // 16KB o-gate (last step)

  const int tid  = threadIdx.x;
  const int wid  = tid >> 6;
  const int lane = tid & 63;
  const int mg   = blockIdx.x & 7;
  const int ng   = blockIdx.x >> 3;
  const int mbase = mg*32;
  const int nbase = ng*32;

  const int mh_w = wid & 1;
  const int q_w  = wid >> 1;

  // ---- B (i,f gates; both 16-col halves; this wave's k-quarter) into VGPRs ----
  const int bcol0 = nbase + (lane&15);
  const int bcol1 = nbase + 16 + (lane&15);
  const int bk    = q_w*256 + (lane>>4)*8;
  f16x8 Bi0[8], Bi1[8], Bf0[8], Bf1[8];
  #pragma unroll
  for(int kk=0;kk<8;kk++){
    Bi0[kk] = *reinterpret_cast<const f16x8*>(wTi + bcol0*1024 + bk + kk*32);
    Bi1[kk] = *reinterpret_cast<const f16x8*>(wTi + bcol1*1024 + bk + kk*32);
    Bf0[kk] = *reinterpret_cast<const f16x8*>(wTf + bcol0*1024 + bk + kk*32);
    Bf1[kk] = *reinterpret_cast<const f16x8*>(wTf + bcol1*1024 + bk + kk*32);
  }

  const int b_l = tid >> 4;            // owned batch row 0..31
  const int h_l = (tid & 15)*2;        // owned col pair in slice
  const int bg  = mbase + b_l;

  float tT[3][3][2];
  { const float* Tp[3] = {Ti, Tf, Tc};
    #pragma unroll
    for(int g=0; g<3; g++)
      #pragma unroll
      for(int v=0; v<3; v++)
        #pragma unroll
        for(int j=0; j<2; j++) tT[g][v][j] = Tp[g][v*1024 + nbase + h_l + j];
  }
  float cm0 = 0.f, cm1 = 0.f;          // master c in f32

  const int arow = mh_w*16 + (lane&15);          // global row offset within group
  const int aoff = q_w*256 + (lane>>4)*8;        // element offset within row
  unsigned int* arr = bars + mg*64;

  int vc = x[bg*512];

  for(int t=0; t<NSTEP; t++){
    const bool last = (t == NSTEP-1);
    const unsigned short* rdp = cbf + (unsigned)(t&1)*262144u;
    unsigned short*       wrp = cbf + (unsigned)((t+1)&1)*262144u;

    // ---- per-wave poll: the 8 producers of this wave's k-quarter ----
    if(t > 0){
      const unsigned tgt = (unsigned)t;
      const unsigned* slot = arr + q_w*8 + (lane&7);
      while(true){
        unsigned v = ld32_coh(slot);
        if(__all((int)(v >= tgt))) break;
        __builtin_amdgcn_s_sleep(1);
      }
    }

    // ---- A fragments straight from the coherent plane (no LDS staging) ----
    f16x8 ah[8];
    ldA8_coh(rdp + (mbase + arow)*1024 + aoff, ah);
    int vn = last ? 0 : x[bg*512 + t + 1];

    // ---- 32 MFMA: i,f gates x 2 col-halves x 8 k-slices ----
    f32x4 a00={0.f,0.f,0.f,0.f}, a01={0.f,0.f,0.f,0.f};
    f32x4 a10={0.f,0.f,0.f,0.f}, a11={0.f,0.f,0.f,0.f};
    #pragma unroll
    for(int kk=0;kk<8;kk++){
      a00 = __builtin_amdgcn_mfma_f32_16x16x32_f16(ah[kk], Bi0[kk], a00, 0,0,0);
      a01 = __builtin_amdgcn_mfma_f32_16x16x32_f16(ah[kk], Bi1[kk], a01, 0,0,0);
      a10 = __builtin_amdgcn_mfma_f32_16x16x32_f16(ah[kk], Bf0[kk], a10, 0,0,0);
      a11 = __builtin_amdgcn_mfma_f32_16x16x32_f16(ah[kk], Bf1[kk], a11, 0,0,0);
    }
    *reinterpret_cast<f32x4*>(xch + (wid*4 + 0)*256 + lane*4) = a00;
    *reinterpret_cast<f32x4*>(xch + (wid*4 + 1)*256 + lane*4) = a01;
    *reinterpret_cast<f32x4*>(xch + (wid*4 + 2)*256 + lane*4) = a10;
    *reinterpret_cast<f32x4*>(xch + (wid*4 + 3)*256 + lane*4) = a11;
    if(last){
      f32x4 o0={0.f,0.f,0.f,0.f}, o1={0.f,0.f,0.f,0.f};
      #pragma unroll
      for(int kk=0;kk<8;kk++){
        f16x8 bo0 = *reinterpret_cast<const f16x8*>(wTo + bcol0*1024 + bk + kk*32);
        f16x8 bo1 = *reinterpret_cast<const f16x8*>(wTo + bcol1*1024 + bk + kk*32);
        o0 = __builtin_amdgcn_mfma_f32_16x16x32_f16(ah[kk], bo0, o0, 0,0,0);
        o1 = __builtin_amdgcn_mfma_f32_16x16x32_f16(ah[kk], bo1, o1, 0,0,0);
      }
      *reinterpret_cast<f32x4*>(xo + (wid*2 + 0)*256 + lane*4) = o0;
      *reinterpret_cast<f32x4*>(xo + (wid*2 + 1)*256 + lane*4) = o1;
    }
    __syncthreads();

    // ---- elementwise update: each thread owns 2 c elements ----
    {
      const int v = vc;
      int r16 = b_l & 15;
      int mh  = b_l >> 4;
      int reg = r16 & 3;
      int lq  = r16 >> 2;
      float cn[2], hh[2];
      #pragma unroll
      for(int j=0;j<2;j++){
        int col = h_l + j;
        int nh  = col >> 4;
        int l   = (lq<<4) | (col & 15);
        float mi = 0.f, mf = 0.f;
        #pragma unroll
        for(int q=0;q<4;q++){
          const float* base = xch + ((q*2+mh)*4 + nh)*256 + l*4 + reg;
          mi += base[0];
          mf += base[512];
        }
        float ti = (v==0)?tT[0][0][j]:(v==1)?tT[0][1][j]:tT[0][2][j];
        float tf = (v==0)?tT[1][0][j]:(v==1)?tT[1][1][j]:tT[1][2][j];
        float tc = (v==0)?tT[2][0][j]:(v==1)?tT[2][1][j]:tT[2][2][j];
        float iv = sigf(ti + mi);
        float fv = sigf(tf + mf);
        float cv = sigf(tc);
        float cm = j ? cm1 : cm0;
        float c2 = cv*iv + cm*fv;
        cn[j] = c2;
        if(last){
          float mo = 0.f;
          #pragma unroll
          for(int q=0;q<4;q++) mo += xo[((q*2+mh)*2 + nh)*256 + l*4 + reg];
          float to = To[v*1024 + nbase + col];
          float ov = sigf(to + mo);
          float pad = (float)((v+1)>>1);
          hh[j] = tanhf(c2)*ov*pad;
        }
      }
      if(!last){
        cm0 = cn[0]; cm1 = cn[1];
        unsigned pk = (unsigned)f2h(cn[0]) | (((unsigned)f2h(cn[1]))<<16);
        st32_coh(reinterpret_cast<unsigned*>(wrp + bg*1024 + nbase + h_l), pk);
      } else {
        *reinterpret_cast<float2*>(hbuf + bg*1024 + nbase + h_l) = make_float2(hh[0], hh[1]);
      }
    }

    if(!last){
      __syncthreads();   // every thread drained its coherent publish (in-asm waitcnt)
      if(tid == 0) st32_coh(&arr[ng], (unsigned)(t+1));
    }
    vc = vn;
  }
}

// ---- projection + log_softmax over axis 0 (batch) ----
__global__ void k_proj(const float* __restrict__ hbuf, const float* __restrict__ w_ph,
                       const float* __restrict__ b_p, float* __restrict__ out){
  const int c = blockIdx.x;    // 0..9
  const int b = threadIdx.x;   // 0..255
  float acc = b_p[c];
  const float4* hb = reinterpret_cast<const float4*>(hbuf + b*1024);
  for(int i=0;i<256;i++){
    float4 hv = hb[i];
    int h = i*4;
    acc += hv.x*w_ph[h*10+c] + hv.y*w_ph[(h+1)*10+c] + hv.z*w_ph[(h+2)*10+c] + hv.w*w_ph[(h+3)*10+c];
  }
  __shared__ float red[256];
  red[b] = acc; __syncthreads();
  for(int s=128;s>0;s>>=1){ if(b<s) red[b]=fmaxf(red[b],red[b+s]); __syncthreads(); }
  float m = red[0]; __syncthreads();
  red[b] = expf(acc-m); __syncthreads();
  for(int s=128;s>0;s>>=1){ if(b<s) red[b]+=red[b+s]; __syncthreads(); }
  out[b*10+c] = acc - m - logf(red[0]);
}

extern "C" void kernel_launch(void* const* d_in, const int* in_sizes, int n_in,
                              void* d_out, int out_size, void* d_ws, size_t ws_size,
                              hipStream_t stream){
  const int*   x    = (const int*)  d_in[0];
  const float* emb  = (const float*)d_in[1];
  const float* w_cx = (const float*)d_in[2];
  const float* b_c  = (const float*)d_in[3];
  const float* w_ix = (const float*)d_in[4];
  const float* w_ih = (const float*)d_in[5];
  const float* b_i  = (const float*)d_in[6];
  const float* w_fx = (const float*)d_in[7];
  const float* w_fh = (const float*)d_in[8];
  const float* b_f  = (const float*)d_in[9];
  const float* w_ox = (const float*)d_in[10];
  const float* w_oh = (const float*)d_in[11];
  const float* b_o  = (const float*)d_in[12];
  const float* w_ph = (const float*)d_in[13];
  const float* b_p  = (const float*)d_in[14];
  float* out = (float*)d_out;

  char* ws = (char*)d_ws;
  float* Ti = (float*)(ws);
  float* Tf = (float*)(ws + 12288);
  float* To = (float*)(ws + 24576);
  float* Tc = (float*)(ws + 36864);
  unsigned short* wTi = (unsigned short*)(ws + 49152);
  unsigned short* wTf = (unsigned short*)(ws + 2146304);
  unsigned short* wTo = (unsigned short*)(ws + 4243456);
  unsigned short* cbf = (unsigned short*)(ws + 6340608);  // 2 planes x 512KB f16
  unsigned int*  bars = (unsigned int*) (ws + 7389184);   // 8 groups x 64 dword flags
  float* hbuf = (float*)(ws + 7391232);

  hipMemsetAsync(cbf, 0, 1048576 + 2048, stream);   // c planes + flags
  k_tables<<<4,256,0,stream>>>(emb, w_ix, b_i, Ti);
  k_tables<<<4,256,0,stream>>>(emb, w_fx, b_f, Tf);
  k_tables<<<4,256,0,stream>>>(emb, w_ox, b_o, To);
  k_tables<<<4,256,0,stream>>>(emb, w_cx, b_c, Tc);
  k_transpose<<<256,256,0,stream>>>(w_ih, wTi);
  k_transpose<<<256,256,0,stream>>>(w_fh, wTf);
  k_transpose<<<256,256,0,stream>>>(w_oh, wTo);

  void* args[] = { (void*)&x, (void*)&wTi, (void*)&wTf, (void*)&wTo,
                   (void*)&Ti, (void*)&Tf, (void*)&To, (void*)&Tc,
                   (void*)&cbf, (void*)&hbuf, (void*)&bars };
  hipLaunchCooperativeKernel((void*)k_recur, dim3(256), dim3(512), args, 0, stream);
  k_proj<<<10,256,0,stream>>>(hbuf, w_ph, b_p, out);
}